// Round 1
// baseline (869.489 us; speedup 1.0000x reference)
//
#include <hip/hip_runtime.h>

#define Bb 8
#define Ss 2048
#define Tt 2048
#define Dd 1024
#define Oo 1024
#define NEG_BIG -1.0e16f

typedef unsigned short u16;
typedef __attribute__((ext_vector_type(4))) float f32x4;
typedef __attribute__((ext_vector_type(8))) _Float16 f16x8;
typedef __attribute__((ext_vector_type(8))) u16 u16x8;
typedef __attribute__((ext_vector_type(4))) u16 u16x4;

__device__ __forceinline__ u16 f2h(float x) {
  return __builtin_bit_cast(u16, (_Float16)x);
}

__device__ __forceinline__ void gload_lds16(const void* g, void* l) {
  __builtin_amdgcn_global_load_lds(
      (__attribute__((address_space(1))) void*)const_cast<void*>(g),
      (__attribute__((address_space(3))) void*)l, 16, 0, 0);
}

__device__ __forceinline__ f16x8 ldfrag(const u16* p) {
  return __builtin_bit_cast(f16x8, *(const u16x8*)p);
}

// ---------------- prep: f32 -> fp16 elementwise ----------------
__global__ __launch_bounds__(256) void cvt_f16(const float* __restrict__ in,
                                               u16* __restrict__ out16) {
  const size_t i = ((size_t)blockIdx.x * 256 + threadIdx.x) * 4;
  float4 v = *(const float4*)(in + i);
  u16x4 h = {f2h(v.x), f2h(v.y), f2h(v.z), f2h(v.w)};
  *(u16x4*)(out16 + i) = h;
}

// ---------------- prep: src f32 -> src16 fp16 [B,S,D] + srcT fp16 [B,D,S] ----
__global__ __launch_bounds__(256) void prep_src(const float* __restrict__ src,
                                                u16* __restrict__ src16,
                                                u16* __restrict__ srcT) {
  __shared__ u16 tile[64][72];
  const int b = blockIdx.z;
  const int d0 = blockIdx.x * 64;
  const int s0 = blockIdx.y * 64;
  const int tid = threadIdx.x;
  const int sl = tid >> 4;          // 0..15
  const int dl = (tid & 15) * 4;    // 0..60
#pragma unroll
  for (int p = 0; p < 4; ++p) {
    const int srow = s0 + sl + p * 16;
    float4 v = *(const float4*)(src + ((size_t)b * Ss + srow) * Dd + d0 + dl);
    u16 h0 = f2h(v.x), h1 = f2h(v.y), h2 = f2h(v.z), h3 = f2h(v.w);
    *(u16x4*)(src16 + ((size_t)b * Ss + srow) * Dd + d0 + dl) = (u16x4){h0, h1, h2, h3};
    tile[dl + 0][sl + p * 16] = h0;
    tile[dl + 1][sl + p * 16] = h1;
    tile[dl + 2][sl + p * 16] = h2;
    tile[dl + 3][sl + p * 16] = h3;
  }
  __syncthreads();
  const int dl2 = tid >> 4;
  const int sl2 = (tid & 15) * 4;
#pragma unroll
  for (int p = 0; p < 4; ++p) {
    const int drow = d0 + dl2 + p * 16;
    u16x4 vv = {tile[dl2 + p * 16][sl2], tile[dl2 + p * 16][sl2 + 1],
                tile[dl2 + p * 16][sl2 + 2], tile[dl2 + p * 16][sl2 + 3]};
    *(u16x4*)(srcT + ((size_t)b * Dd + drow) * Ss + s0 + sl2) = vv;
  }
}

// ---------------- GEMM: C = A (MxK) * B^T (NxK), fp16 MFMA 16x16x32 -----------
// MODE 0: scores = tgt16 * src16^T + mask*NEG_BIG  -> f32 (scores region)
// MODE 1: wsum   = w16 * srcT^T                    -> fp16
// MODE 2: out    = [wsum|tgt16] * W16^T + bias     -> f32
template <int MODE>
__global__ __launch_bounds__(256) void gemm16(
    const u16* __restrict__ A, size_t ldA, size_t sA,
    const u16* __restrict__ A2,
    const u16* __restrict__ Bm, size_t ldB, size_t sB,
    int K,
    float* __restrict__ outF, u16* __restrict__ outH,
    const int* __restrict__ mask, const float* __restrict__ bias) {
  __shared__ __align__(16) u16 At[128][32];
  __shared__ __align__(16) u16 Bt[128][32];
  const int b = blockIdx.z;
  const int tm = blockIdx.y, tn = blockIdx.x;
  const int tid = threadIdx.x;
  const int w = tid >> 6, l = tid & 63;
  const int wr = w >> 1, wc = w & 1;
  const int lr = l >> 2, lk = (l & 3) * 8;

  f32x4 acc[4][4];
#pragma unroll
  for (int m = 0; m < 4; ++m)
#pragma unroll
    for (int n = 0; n < 4; ++n) acc[m][n] = (f32x4){0.f, 0.f, 0.f, 0.f};

  const int c0 = 2 * w, c1 = 2 * w + 1;

  for (int k0 = 0; k0 < K; k0 += 32) {
    const u16 *ga0, *ga1;
    if constexpr (MODE == 2) {
      const u16* base = (k0 < Dd) ? A : A2;
      const int kk = (k0 < Dd) ? k0 : (k0 - Dd);
      ga0 = base + (size_t)b * sA + (size_t)(tm * 128 + c0 * 16 + lr) * 1024 + kk + lk;
      ga1 = base + (size_t)b * sA + (size_t)(tm * 128 + c1 * 16 + lr) * 1024 + kk + lk;
    } else {
      ga0 = A + (size_t)b * sA + (size_t)(tm * 128 + c0 * 16 + lr) * ldA + k0 + lk;
      ga1 = A + (size_t)b * sA + (size_t)(tm * 128 + c1 * 16 + lr) * ldA + k0 + lk;
    }
    gload_lds16(ga0, &At[c0 * 16][0]);
    gload_lds16(ga1, &At[c1 * 16][0]);
    const u16* gb0 = Bm + (size_t)b * sB + (size_t)(tn * 128 + c0 * 16 + lr) * ldB + k0 + lk;
    const u16* gb1 = Bm + (size_t)b * sB + (size_t)(tn * 128 + c1 * 16 + lr) * ldB + k0 + lk;
    gload_lds16(gb0, &Bt[c0 * 16][0]);
    gload_lds16(gb1, &Bt[c1 * 16][0]);
    __syncthreads();
    f16x8 af[4], bf[4];
#pragma unroll
    for (int m = 0; m < 4; ++m)
      af[m] = ldfrag(&At[wr * 64 + m * 16 + (l & 15)][(l >> 4) * 8]);
#pragma unroll
    for (int n = 0; n < 4; ++n)
      bf[n] = ldfrag(&Bt[wc * 64 + n * 16 + (l & 15)][(l >> 4) * 8]);
#pragma unroll
    for (int m = 0; m < 4; ++m)
#pragma unroll
      for (int n = 0; n < 4; ++n)
        acc[m][n] = __builtin_amdgcn_mfma_f32_16x16x32_f16(af[m], bf[n], acc[m][n], 0, 0, 0);
    __syncthreads();
  }

  const int fr = l & 15, fq = l >> 4;
  const int r0 = tm * 128 + wr * 64;
  const int col0 = tn * 128 + wc * 64;
#pragma unroll
  for (int m = 0; m < 4; ++m) {
#pragma unroll
    for (int n = 0; n < 4; ++n) {
#pragma unroll
      for (int j = 0; j < 4; ++j) {
        const int r = r0 + m * 16 + fq * 4 + j;
        const int c = col0 + n * 16 + fr;
        float v = acc[m][n][j];
        if constexpr (MODE == 0) {
          const int mk = mask[((size_t)r * Bb + b) * Ss + c];
          v += (float)mk * NEG_BIG;
          outF[((size_t)b * Tt + r) * Ss + c] = v;
        } else if constexpr (MODE == 1) {
          outH[((size_t)b * Tt + r) * Dd + c] = f2h(v);
        } else {
          outF[((size_t)b * Tt + r) * Oo + c] = v + bias[c];
        }
      }
    }
  }
}

// ---------------- column (axis=t) softmax stats: m, 1/l per (b,s) ------------
__global__ __launch_bounds__(256) void colstats(const float* __restrict__ sc,
                                                float* __restrict__ mcol,
                                                float* __restrict__ rlcol) {
  const int b = blockIdx.y;
  const int c = threadIdx.x & 31;
  const int seg = threadIdx.x >> 5;  // 0..7, each covers 256 t-rows
  const int s = blockIdx.x * 32 + c;
  const float* p = sc + ((size_t)b * Tt + seg * 256) * Ss + s;
  float m = -3.0e38f, lsum = 0.0f;
#pragma unroll 4
  for (int i = 0; i < 256; ++i) {
    float v = p[(size_t)i * Ss];
    float mn = fmaxf(m, v);
    lsum = lsum * __expf(m - mn) + __expf(v - mn);
    m = mn;
  }
  __shared__ float sm[8][32], sl[8][32];
  sm[seg][c] = m;
  sl[seg][c] = lsum;
  __syncthreads();
  if (seg == 0) {
    float M = sm[0][c];
#pragma unroll
    for (int k = 1; k < 8; ++k) M = fmaxf(M, sm[k][c]);
    float L = 0.0f;
#pragma unroll
    for (int k = 0; k < 8; ++k) L += sl[k][c] * __expf(sm[k][c] - M);
    mcol[(size_t)b * Ss + s] = M;
    rlcol[(size_t)b * Ss + s] = 1.0f / L;
  }
}

// ---------------- normalize: weight f32 (in place, d_out) + fp16 copy --------
__global__ __launch_bounds__(256) void normalize(float* __restrict__ sc,
                                                 const float* __restrict__ mcol,
                                                 const float* __restrict__ rlcol,
                                                 u16* __restrict__ w16) {
  const size_t i = ((size_t)blockIdx.x * 256 + threadIdx.x) * 4;
  const int s = (int)(i & (Ss - 1));
  const size_t bt = i >> 11;
  const int b = (int)(bt >> 11);
  float4 v = *(const float4*)(sc + i);
  float4 m4 = *(const float4*)(mcol + (size_t)b * Ss + s);
  float4 r4 = *(const float4*)(rlcol + (size_t)b * Ss + s);
  float w0 = __expf(v.x - m4.x) * r4.x;
  float w1 = __expf(v.y - m4.y) * r4.y;
  float w2 = __expf(v.z - m4.z) * r4.z;
  float w3 = __expf(v.w - m4.w) * r4.w;
  *(float4*)(sc + i) = make_float4(w0, w1, w2, w3);
  *(u16x4*)(w16 + i) = (u16x4){f2h(w0), f2h(w1), f2h(w2), f2h(w3)};
}

extern "C" void kernel_launch(void* const* d_in, const int* in_sizes, int n_in,
                              void* d_out, int out_size, void* d_ws, size_t ws_size,
                              hipStream_t stream) {
  const float* src = (const float*)d_in[0];   // [B,S,D]
  const float* tgt = (const float*)d_in[1];   // [B,T,D]
  const int* mask = (const int*)d_in[2];      // [T,B,S]
  const float* W = (const float*)d_in[3];     // [O,2D]
  const float* bias = (const float*)d_in[4];  // [O]
  float* out = (float*)d_out;                       // [B,T,O]
  float* scores = out + (size_t)Bb * Tt * Oo;       // [B,T,S] (weight output region)

  u16* tgt16 = (u16*)d_ws;                          // fp16 [B,T,D]
  u16* src16 = tgt16 + (size_t)Bb * Tt * Dd;        // fp16 [B,S,D]
  u16* srcT = src16 + (size_t)Bb * Ss * Dd;         // fp16 [B,D,S]
  u16* wsum16 = srcT + (size_t)Bb * Dd * Ss;        // fp16 [B,T,D]
  u16* w16 = wsum16 + (size_t)Bb * Tt * Dd;         // fp16 [B,T,S]
  u16* W16 = w16 + (size_t)Bb * Tt * Ss;            // fp16 [O,2D]
  float* mcol = (float*)(W16 + (size_t)Oo * 2 * Dd);  // [B,S]
  float* rlcol = mcol + (size_t)Bb * Ss;              // [B,S]

  // prep
  cvt_f16<<<(Bb * Tt * Dd) / 1024, 256, 0, stream>>>(tgt, tgt16);
  cvt_f16<<<(Oo * 2 * Dd) / 1024, 256, 0, stream>>>(W, W16);
  prep_src<<<dim3(Dd / 64, Ss / 64, Bb), 256, 0, stream>>>(src, src16, srcT);

  // GEMM1: scores = tgt * src^T + mask*NEG_BIG
  gemm16<0><<<dim3(Ss / 128, Tt / 128, Bb), 256, 0, stream>>>(
      tgt16, (size_t)Dd, (size_t)Tt * Dd, nullptr,
      src16, (size_t)Dd, (size_t)Ss * Dd, Dd,
      scores, nullptr, mask, nullptr);

  // column softmax over t
  colstats<<<dim3(Ss / 32, Bb), 256, 0, stream>>>(scores, mcol, rlcol);
  normalize<<<(size_t)(Bb * Tt) * Ss / 1024, 256, 0, stream>>>(scores, mcol, rlcol, w16);

  // GEMM2: wsum = weight * src  (via srcT, A*B^T form)
  gemm16<1><<<dim3(Dd / 128, Tt / 128, Bb), 256, 0, stream>>>(
      w16, (size_t)Ss, (size_t)Tt * Ss, nullptr,
      srcT, (size_t)Ss, (size_t)Dd * Ss, Ss,
      nullptr, wsum16, nullptr, nullptr);

  // GEMM3: out = [wsum|tgt] * W^T + bias
  gemm16<2><<<dim3(Oo / 128, Tt / 128, Bb), 256, 0, stream>>>(
      wsum16, (size_t)Dd, (size_t)Tt * Dd, tgt16,
      W16, (size_t)2 * Dd, (size_t)0, 2 * Dd,
      out, nullptr, nullptr, bias);
}

// Round 2
// 685.973 us; speedup vs baseline: 1.2675x; 1.2675x over previous
//
#include <hip/hip_runtime.h>

#define Bb 8
#define Ss 2048
#define Tt 2048
#define Dd 1024
#define Oo 1024
#define NEG_BIG -1.0e16f

typedef unsigned short u16;
typedef __attribute__((ext_vector_type(4))) float f32x4;
typedef __attribute__((ext_vector_type(8))) _Float16 f16x8;
typedef __attribute__((ext_vector_type(8))) u16 u16x8;
typedef __attribute__((ext_vector_type(4))) u16 u16x4;

__device__ __forceinline__ u16 f2h(float x) {
  return __builtin_bit_cast(u16, (_Float16)x);
}

__device__ __forceinline__ void gload_lds16(const void* g, void* l) {
  __builtin_amdgcn_global_load_lds(
      (__attribute__((address_space(1))) void*)const_cast<void*>(g),
      (__attribute__((address_space(3))) void*)l, 16, 0, 0);
}

__device__ __forceinline__ f16x8 ldfrag(const u16* p) {
  return __builtin_bit_cast(f16x8, *(const u16x8*)p);
}

// ---------------- prep: f32 -> fp16 elementwise ----------------
__global__ __launch_bounds__(256) void cvt_f16(const float* __restrict__ in,
                                               u16* __restrict__ out16) {
  const size_t i = ((size_t)blockIdx.x * 256 + threadIdx.x) * 4;
  float4 v = *(const float4*)(in + i);
  u16x4 h = {f2h(v.x), f2h(v.y), f2h(v.z), f2h(v.w)};
  *(u16x4*)(out16 + i) = h;
}

// ---------------- prep: src f32 -> src16 fp16 [B,S,D] + srcT fp16 [B,D,S] ----
__global__ __launch_bounds__(256) void prep_src(const float* __restrict__ src,
                                                u16* __restrict__ src16,
                                                u16* __restrict__ srcT) {
  __shared__ u16 tile[64][72];
  const int b = blockIdx.z;
  const int d0 = blockIdx.x * 64;
  const int s0 = blockIdx.y * 64;
  const int tid = threadIdx.x;
  const int sl = tid >> 4;          // 0..15
  const int dl = (tid & 15) * 4;    // 0..60
#pragma unroll
  for (int p = 0; p < 4; ++p) {
    const int srow = s0 + sl + p * 16;
    float4 v = *(const float4*)(src + ((size_t)b * Ss + srow) * Dd + d0 + dl);
    u16 h0 = f2h(v.x), h1 = f2h(v.y), h2 = f2h(v.z), h3 = f2h(v.w);
    *(u16x4*)(src16 + ((size_t)b * Ss + srow) * Dd + d0 + dl) = (u16x4){h0, h1, h2, h3};
    tile[dl + 0][sl + p * 16] = h0;
    tile[dl + 1][sl + p * 16] = h1;
    tile[dl + 2][sl + p * 16] = h2;
    tile[dl + 3][sl + p * 16] = h3;
  }
  __syncthreads();
  const int dl2 = tid >> 4;
  const int sl2 = (tid & 15) * 4;
#pragma unroll
  for (int p = 0; p < 4; ++p) {
    const int drow = d0 + dl2 + p * 16;
    u16x4 vv = {tile[dl2 + p * 16][sl2], tile[dl2 + p * 16][sl2 + 1],
                tile[dl2 + p * 16][sl2 + 2], tile[dl2 + p * 16][sl2 + 3]};
    *(u16x4*)(srcT + ((size_t)b * Dd + drow) * Ss + s0 + sl2) = vv;
  }
}

// ================= 256x256 8-phase GEMM (T2+T3+T4+T5) ========================
// C = A (Mx K) * B^T (N x K), fp16 MFMA 16x16x32, BM=BN=256, BK=64.
// 8 waves (2M x 4N), 512 threads, 1 block/CU. LDS: 2 dbuf x (A 32KB + B 32KB)
// + 2KB dummy = 130KB. Staging: global_load_lds w16, linear LDS dest,
// pre-swizzled global source col (byte ^= (row&7)<<4); ds_read applies same XOR.
// Half-tile rotation lead-6; vmcnt(4) only at K-tile boundaries.
// MODE 0: scores = tgt16 * src16^T + mask*NEG_BIG -> f32
// MODE 1: wsum   = w16 * srcT^T                   -> fp16
// MODE 2: out    = [wsum|tgt16] * W16^T + bias    -> f32 (rows b*T+r)
template <int MODE>
__global__ __launch_bounds__(512, 2) void gemm256(
    const u16* __restrict__ A, size_t ldA, size_t sA,
    const u16* __restrict__ A2,
    const u16* __restrict__ Bm, size_t ldB, size_t sB,
    int NT,
    float* __restrict__ outF, u16* __restrict__ outH,
    const int* __restrict__ mask, const float* __restrict__ bias) {
  // u16 layout: A buf d at d*16384 (each 16384 u16 = 256x64), B at 32768+d*16384,
  // dummy at 65536 (1024 u16)
  __shared__ __align__(16) u16 sh[66560];
  const int b = blockIdx.z;
  const int tn = blockIdx.x, tm = blockIdx.y;
  const int tid = threadIdx.x;
  const int w = tid >> 6, l = tid & 63;
  const int wr = w >> 2, wc = w & 3;

  // staging: per wave 2 instrs x 1KB; lane covers rows r = w*16 + i*8 + (l>>3),
  // linear colbyte (l&7)*16; swizzled source colbyte = ((l&7)^(l>>3))<<4
  const int sr0 = w * 16 + (l >> 3);
  const int scb = (((l & 7) ^ (l >> 3)) << 4);
  // frag read swizzled col offsets (u16), ksub 0/1: (ksub*64 + (l>>4)*16) ^ ((l&7)<<4)
  const int fc0 = (((l >> 4) * 16) ^ ((l & 7) << 4)) >> 1;
  const int fc1 = ((64 + (l >> 4) * 16) ^ ((l & 7) << 4)) >> 1;

  auto STAGE = [&](int isB, int ds, int hh, int ts) {
    int dst = (isB ? 32768 : 0) + ds * 16384 + hh * 8192 + w * 1024;
    if (ts >= NT) { ts = NT - 1; dst = 65536; }
    const u16* srcBase;
    size_t ld;
    int rowBase;
    int kbyte = ts * 128;
    if (isB) {
      srcBase = Bm + (size_t)b * sB;
      ld = ldB;
      rowBase = tn * 256 + hh * 128;
    } else {
      if constexpr (MODE == 2) {
        srcBase = (ts < 16 ? A : A2) + (size_t)b * sA;
        kbyte = (ts & 15) * 128;
      } else {
        srcBase = A + (size_t)b * sA;
      }
      ld = ldA;
      rowBase = tm * 256 + hh * 128;
    }
    const char* s0 = (const char*)srcBase + (size_t)(rowBase + sr0) * (ld * 2) + kbyte + scb;
    const char* s1 = (const char*)srcBase + (size_t)(rowBase + sr0 + 8) * (ld * 2) + kbyte + scb;
    gload_lds16(s0, &sh[dst]);
    gload_lds16(s1, &sh[dst + 512]);
  };

  f32x4 acc[8][4];
#pragma unroll
  for (int m = 0; m < 8; ++m)
#pragma unroll
    for (int n = 0; n < 4; ++n) acc[m][n] = (f32x4){0.f, 0.f, 0.f, 0.f};
  f16x8 bf[4][2], af[2][2];

  // prologue: H0..H5 = B(0)h0, B(0)h1, A(0)h0, A(0)h1, B(1)h0, B(1)h1
  STAGE(1, 0, 0, 0);
  STAGE(1, 0, 1, 0);
  STAGE(0, 0, 0, 0);
  STAGE(0, 0, 1, 0);
  STAGE(1, 1, 0, 1);
  STAGE(1, 1, 1, 1);
  asm volatile("s_waitcnt vmcnt(4)" ::: "memory");
  asm volatile("s_barrier" ::: "memory");

  const int NITER = NT >> 1;
  for (int it = 0; it < NITER; ++it) {
#pragma unroll
    for (int p = 0; p < 8; ++p) {
      const int q = p & 3, d = (p >> 2) & 1;
      if (q == 0) {
#pragma unroll
        for (int ni = 0; ni < 4; ++ni) {
          const int rb = wc * 64 + ni * 16 + (l & 15);
          bf[ni][0] = ldfrag(&sh[32768 + d * 16384 + rb * 64 + fc0]);
          bf[ni][1] = ldfrag(&sh[32768 + d * 16384 + rb * 64 + fc1]);
        }
      }
#pragma unroll
      for (int mi = 0; mi < 2; ++mi) {
        const int ra = wr * 128 + q * 32 + mi * 16 + (l & 15);
        af[mi][0] = ldfrag(&sh[d * 16384 + ra * 64 + fc0]);
        af[mi][1] = ldfrag(&sh[d * 16384 + ra * 64 + fc1]);
      }
      // stage H_{8it+p+6}: sub 0,1 = B h0,h1 ; sub 2,3 = A h0,h1 (of tile j>>2)
      {
        const int j = 8 * it + p + 6;
        const int ts = j >> 2, sub = j & 3;
        STAGE(sub < 2, ts & 1, sub & 1, ts);
      }
      if (q == 3) asm volatile("s_waitcnt vmcnt(4)" ::: "memory");
      asm volatile("s_barrier" ::: "memory");
      __builtin_amdgcn_s_setprio(1);
#pragma unroll
      for (int mi = 0; mi < 2; ++mi)
#pragma unroll
        for (int ni = 0; ni < 4; ++ni) {
          acc[2 * q + mi][ni] = __builtin_amdgcn_mfma_f32_16x16x32_f16(
              af[mi][0], bf[ni][0], acc[2 * q + mi][ni], 0, 0, 0);
          acc[2 * q + mi][ni] = __builtin_amdgcn_mfma_f32_16x16x32_f16(
              af[mi][1], bf[ni][1], acc[2 * q + mi][ni], 0, 0, 0);
        }
      __builtin_amdgcn_s_setprio(0);
      asm volatile("s_barrier" ::: "memory");
    }
  }

  // epilogue
  const int fr = l & 15, fq = l >> 4;
  const int r0 = tm * 256 + wr * 128;
  const int c0 = tn * 256 + wc * 64;
#pragma unroll
  for (int m = 0; m < 8; ++m) {
#pragma unroll
    for (int n = 0; n < 4; ++n) {
#pragma unroll
      for (int j = 0; j < 4; ++j) {
        const int r = r0 + m * 16 + fq * 4 + j;
        const int c = c0 + n * 16 + fr;
        float v = acc[m][n][j];
        if constexpr (MODE == 0) {
          const int mk = mask[((size_t)r * Bb + b) * Ss + c];
          v += (float)mk * NEG_BIG;
          outF[((size_t)b * Tt + r) * Ss + c] = v;
        } else if constexpr (MODE == 1) {
          outH[((size_t)b * Tt + r) * Dd + c] = f2h(v);
        } else {
          outF[((size_t)b * Tt + r) * Oo + c] = v + bias[c];
        }
      }
    }
  }
}

// ---------------- column (axis=t) softmax stats: m, 1/l per (b,s) ------------
__global__ __launch_bounds__(256) void colstats(const float* __restrict__ sc,
                                                float* __restrict__ mcol,
                                                float* __restrict__ rlcol) {
  const int b = blockIdx.y;
  const int c = threadIdx.x & 31;
  const int seg = threadIdx.x >> 5;  // 0..7, each covers 256 t-rows
  const int s = blockIdx.x * 32 + c;
  const float* p = sc + ((size_t)b * Tt + seg * 256) * Ss + s;
  float m = -3.0e38f, lsum = 0.0f;
#pragma unroll 4
  for (int i = 0; i < 256; ++i) {
    float v = p[(size_t)i * Ss];
    float mn = fmaxf(m, v);
    lsum = lsum * __expf(m - mn) + __expf(v - mn);
    m = mn;
  }
  __shared__ float sm[8][32], sl[8][32];
  sm[seg][c] = m;
  sl[seg][c] = lsum;
  __syncthreads();
  if (seg == 0) {
    float M = sm[0][c];
#pragma unroll
    for (int k = 1; k < 8; ++k) M = fmaxf(M, sm[k][c]);
    float L = 0.0f;
#pragma unroll
    for (int k = 0; k < 8; ++k) L += sl[k][c] * __expf(sm[k][c] - M);
    mcol[(size_t)b * Ss + s] = M;
    rlcol[(size_t)b * Ss + s] = 1.0f / L;
  }
}

// ---------------- normalize: weight f32 (in place, d_out) + fp16 copy --------
__global__ __launch_bounds__(256) void normalize(float* __restrict__ sc,
                                                 const float* __restrict__ mcol,
                                                 const float* __restrict__ rlcol,
                                                 u16* __restrict__ w16) {
  const size_t i = ((size_t)blockIdx.x * 256 + threadIdx.x) * 4;
  const int s = (int)(i & (Ss - 1));
  const size_t bt = i >> 11;
  const int b = (int)(bt >> 11);
  float4 v = *(const float4*)(sc + i);
  float4 m4 = *(const float4*)(mcol + (size_t)b * Ss + s);
  float4 r4 = *(const float4*)(rlcol + (size_t)b * Ss + s);
  float w0 = __expf(v.x - m4.x) * r4.x;
  float w1 = __expf(v.y - m4.y) * r4.y;
  float w2 = __expf(v.z - m4.z) * r4.z;
  float w3 = __expf(v.w - m4.w) * r4.w;
  *(float4*)(sc + i) = make_float4(w0, w1, w2, w3);
  *(u16x4*)(w16 + i) = (u16x4){f2h(w0), f2h(w1), f2h(w2), f2h(w3)};
}

extern "C" void kernel_launch(void* const* d_in, const int* in_sizes, int n_in,
                              void* d_out, int out_size, void* d_ws, size_t ws_size,
                              hipStream_t stream) {
  const float* src = (const float*)d_in[0];   // [B,S,D]
  const float* tgt = (const float*)d_in[1];   // [B,T,D]
  const int* mask = (const int*)d_in[2];      // [T,B,S]
  const float* W = (const float*)d_in[3];     // [O,2D]
  const float* bias = (const float*)d_in[4];  // [O]
  float* out = (float*)d_out;                       // [B,T,O]
  float* scores = out + (size_t)Bb * Tt * Oo;       // [B,T,S] (weight output region)

  u16* tgt16 = (u16*)d_ws;                          // fp16 [B,T,D]
  u16* src16 = tgt16 + (size_t)Bb * Tt * Dd;        // fp16 [B,S,D]
  u16* srcT = src16 + (size_t)Bb * Ss * Dd;         // fp16 [B,D,S]
  u16* wsum16 = srcT + (size_t)Bb * Dd * Ss;        // fp16 [B,T,D]
  u16* w16 = wsum16 + (size_t)Bb * Tt * Dd;         // fp16 [B,T,S]
  u16* W16 = w16 + (size_t)Bb * Tt * Ss;            // fp16 [O,2D]
  float* mcol = (float*)(W16 + (size_t)Oo * 2 * Dd);  // [B,S]
  float* rlcol = mcol + (size_t)Bb * Ss;              // [B,S]

  // prep
  cvt_f16<<<(Bb * Tt * Dd) / 1024, 256, 0, stream>>>(tgt, tgt16);
  cvt_f16<<<(Oo * 2 * Dd) / 1024, 256, 0, stream>>>(W, W16);
  prep_src<<<dim3(Dd / 64, Ss / 64, Bb), 256, 0, stream>>>(src, src16, srcT);

  // GEMM1: scores = tgt * src^T + mask*NEG_BIG   (M=T, N=S, K=D; NT=16)
  gemm256<0><<<dim3(Ss / 256, Tt / 256, Bb), 512, 0, stream>>>(
      tgt16, (size_t)Dd, (size_t)Tt * Dd, nullptr,
      src16, (size_t)Dd, (size_t)Ss * Dd, Dd / 64,
      scores, nullptr, mask, nullptr);

  // column softmax over t
  colstats<<<dim3(Ss / 32, Bb), 256, 0, stream>>>(scores, mcol, rlcol);
  normalize<<<(size_t)(Bb * Tt) * Ss / 1024, 256, 0, stream>>>(scores, mcol, rlcol, w16);

  // GEMM2: wsum = weight * src  (via srcT; M=T, N=D, K=S; NT=32)
  gemm256<1><<<dim3(Dd / 256, Tt / 256, Bb), 512, 0, stream>>>(
      w16, (size_t)Ss, (size_t)Tt * Ss, nullptr,
      srcT, (size_t)Ss, (size_t)Dd * Ss, Ss / 64,
      nullptr, wsum16, nullptr, nullptr);

  // GEMM3: out = [wsum|tgt] * W^T + bias  (M=T, N=O, K=2D; NT=32)
  gemm256<2><<<dim3(Oo / 256, Tt / 256, Bb), 512, 0, stream>>>(
      wsum16, (size_t)Dd, (size_t)Tt * Dd, tgt16,
      W16, (size_t)2 * Dd, (size_t)0, 2 * Dd / 64,
      out, nullptr, nullptr, bias);
}

// Round 3
// 668.101 us; speedup vs baseline: 1.3014x; 1.0268x over previous
//
#include <hip/hip_runtime.h>

#define Bb 8
#define Ss 2048
#define Tt 2048
#define Dd 1024
#define Oo 1024
#define NEG_BIG -1.0e16f

typedef unsigned short u16;
typedef unsigned int u32;
typedef __attribute__((ext_vector_type(4))) float f32x4;
typedef __attribute__((ext_vector_type(8))) _Float16 f16x8;
typedef __attribute__((ext_vector_type(8))) u16 u16x8;
typedef __attribute__((ext_vector_type(4))) u16 u16x4;

__device__ __forceinline__ u16 f2h(float x) {
  return __builtin_bit_cast(u16, (_Float16)x);
}

__device__ __forceinline__ void gload_lds16(const void* g, void* l) {
  __builtin_amdgcn_global_load_lds(
      (__attribute__((address_space(1))) void*)const_cast<void*>(g),
      (__attribute__((address_space(3))) void*)l, 16, 0, 0);
}

__device__ __forceinline__ f16x8 ldfrag(const u16* p) {
  return __builtin_bit_cast(f16x8, *(const u16x8*)p);
}

// ---------------- prep: f32 -> fp16 elementwise ----------------
__global__ __launch_bounds__(256) void cvt_f16(const float* __restrict__ in,
                                               u16* __restrict__ out16) {
  const size_t i = ((size_t)blockIdx.x * 256 + threadIdx.x) * 4;
  float4 v = *(const float4*)(in + i);
  u16x4 h = {f2h(v.x), f2h(v.y), f2h(v.z), f2h(v.w)};
  *(u16x4*)(out16 + i) = h;
}

// ---------------- prep: mask i32 [T,B,S] -> bitmask [B,T,S/32] ---------------
__global__ __launch_bounds__(256) void pack_mask(const int* __restrict__ mask,
                                                 u32* __restrict__ bits) {
  // one thread per output word: word (b,t,sw) <- mask[t][b][sw*32..+31]
  const size_t widx = (size_t)blockIdx.x * 256 + threadIdx.x;  // b*T*(S/32)+t*(S/32)+sw
  const int sw = (int)(widx & (Ss / 32 - 1));
  const int t = (int)((widx >> 6) & (Tt - 1));
  const int b = (int)(widx >> 17);  // T*(S/32) = 2048*64 = 2^17
  const int* p = mask + ((size_t)t * Bb + b) * Ss + sw * 32;
  u32 w = 0;
#pragma unroll
  for (int q = 0; q < 8; ++q) {
    int4 v = *(const int4*)(p + q * 4);
    w |= (u32)((v.x != 0) ? 1u : 0u) << (q * 4 + 0);
    w |= (u32)((v.y != 0) ? 1u : 0u) << (q * 4 + 1);
    w |= (u32)((v.z != 0) ? 1u : 0u) << (q * 4 + 2);
    w |= (u32)((v.w != 0) ? 1u : 0u) << (q * 4 + 3);
  }
  bits[widx] = w;
}

// ---------------- prep: src f32 -> src16 fp16 [B,S,D] + srcT fp16 [B,D,S] ----
__global__ __launch_bounds__(256) void prep_src(const float* __restrict__ src,
                                                u16* __restrict__ src16,
                                                u16* __restrict__ srcT) {
  __shared__ u16 tile[64][72];
  const int b = blockIdx.z;
  const int d0 = blockIdx.x * 64;
  const int s0 = blockIdx.y * 64;
  const int tid = threadIdx.x;
  const int sl = tid >> 4;          // 0..15
  const int dl = (tid & 15) * 4;    // 0..60
#pragma unroll
  for (int p = 0; p < 4; ++p) {
    const int srow = s0 + sl + p * 16;
    float4 v = *(const float4*)(src + ((size_t)b * Ss + srow) * Dd + d0 + dl);
    u16 h0 = f2h(v.x), h1 = f2h(v.y), h2 = f2h(v.z), h3 = f2h(v.w);
    *(u16x4*)(src16 + ((size_t)b * Ss + srow) * Dd + d0 + dl) = (u16x4){h0, h1, h2, h3};
    tile[dl + 0][sl + p * 16] = h0;
    tile[dl + 1][sl + p * 16] = h1;
    tile[dl + 2][sl + p * 16] = h2;
    tile[dl + 3][sl + p * 16] = h3;
  }
  __syncthreads();
  const int dl2 = tid >> 4;
  const int sl2 = (tid & 15) * 4;
#pragma unroll
  for (int p = 0; p < 4; ++p) {
    const int drow = d0 + dl2 + p * 16;
    u16x4 vv = {tile[dl2 + p * 16][sl2], tile[dl2 + p * 16][sl2 + 1],
                tile[dl2 + p * 16][sl2 + 2], tile[dl2 + p * 16][sl2 + 3]};
    *(u16x4*)(srcT + ((size_t)b * Dd + drow) * Ss + s0 + sl2) = vv;
  }
}

// ================= 256x256 8-phase GEMM (T2+T3+T4+T5) ========================
// C = A (M x K) * B^T (N x K), fp16 MFMA 16x16x32, BM=BN=256, BK=64.
// MODE 0: scores = tgt16 * src16^T  -> f32 (raw, mask applied downstream)
// MODE 1: wsum   = w16 * srcT^T     -> fp16
// MODE 2: out    = [wsum|tgt16] * W16^T + bias -> f32
template <int MODE>
__global__ __launch_bounds__(512) void gemm256(
    const u16* __restrict__ A, size_t ldA, size_t sA,
    const u16* __restrict__ A2,
    const u16* __restrict__ Bm, size_t ldB, size_t sB,
    int NT,
    float* __restrict__ outF, u16* __restrict__ outH,
    const float* __restrict__ bias) {
  __shared__ __align__(16) u16 sh[66560];
  const int b = blockIdx.z;
  const int tn = blockIdx.x, tm = blockIdx.y;
  const int tid = threadIdx.x;
  const int w = tid >> 6, l = tid & 63;
  const int wr = w >> 2, wc = w & 3;

  const int sr0 = w * 16 + (l >> 3);
  const int scb = (((l & 7) ^ (l >> 3)) << 4);
  const int fc0 = (((l >> 4) * 16) ^ ((l & 7) << 4)) >> 1;
  const int fc1 = ((64 + (l >> 4) * 16) ^ ((l & 7) << 4)) >> 1;

  auto STAGE = [&](int isB, int ds, int hh, int ts) {
    int dst = (isB ? 32768 : 0) + ds * 16384 + hh * 8192 + w * 1024;
    if (ts >= NT) { ts = NT - 1; dst = 65536; }
    const u16* srcBase;
    size_t ld;
    int rowBase;
    int kbyte = ts * 128;
    if (isB) {
      srcBase = Bm + (size_t)b * sB;
      ld = ldB;
      rowBase = tn * 256 + hh * 128;
    } else {
      if constexpr (MODE == 2) {
        srcBase = (ts < 16 ? A : A2) + (size_t)b * sA;
        kbyte = (ts & 15) * 128;
      } else {
        srcBase = A + (size_t)b * sA;
      }
      ld = ldA;
      rowBase = tm * 256 + hh * 128;
    }
    const char* s0 = (const char*)srcBase + (size_t)(rowBase + sr0) * (ld * 2) + kbyte + scb;
    const char* s1 = (const char*)srcBase + (size_t)(rowBase + sr0 + 8) * (ld * 2) + kbyte + scb;
    gload_lds16(s0, &sh[dst]);
    gload_lds16(s1, &sh[dst + 512]);
  };

  f32x4 acc[8][4];
#pragma unroll
  for (int m = 0; m < 8; ++m)
#pragma unroll
    for (int n = 0; n < 4; ++n) acc[m][n] = (f32x4){0.f, 0.f, 0.f, 0.f};
  f16x8 bf[4][2], af[2][2];

  // prologue: H0..H5 = B(0)h0, B(0)h1, A(0)h0, A(0)h1, B(1)h0, B(1)h1
  STAGE(1, 0, 0, 0);
  STAGE(1, 0, 1, 0);
  STAGE(0, 0, 0, 0);
  STAGE(0, 0, 1, 0);
  STAGE(1, 1, 0, 1);
  STAGE(1, 1, 1, 1);
  asm volatile("s_waitcnt vmcnt(4)" ::: "memory");
  asm volatile("s_barrier" ::: "memory");

  const int NITER = NT >> 1;
  for (int it = 0; it < NITER; ++it) {
#pragma unroll
    for (int p = 0; p < 8; ++p) {
      const int q = p & 3, d = (p >> 2) & 1;
      if (q == 0) {
#pragma unroll
        for (int ni = 0; ni < 4; ++ni) {
          const int rb = wc * 64 + ni * 16 + (l & 15);
          bf[ni][0] = ldfrag(&sh[32768 + d * 16384 + rb * 64 + fc0]);
          bf[ni][1] = ldfrag(&sh[32768 + d * 16384 + rb * 64 + fc1]);
        }
      }
#pragma unroll
      for (int mi = 0; mi < 2; ++mi) {
        const int ra = wr * 128 + q * 32 + mi * 16 + (l & 15);
        af[mi][0] = ldfrag(&sh[d * 16384 + ra * 64 + fc0]);
        af[mi][1] = ldfrag(&sh[d * 16384 + ra * 64 + fc1]);
      }
      {
        const int j = 8 * it + p + 6;
        const int ts = j >> 2, sub = j & 3;
        STAGE(sub < 2, ts & 1, sub & 1, ts);
      }
      if (q == 3) asm volatile("s_waitcnt vmcnt(4)" ::: "memory");
      asm volatile("s_barrier" ::: "memory");
      __builtin_amdgcn_s_setprio(1);
#pragma unroll
      for (int mi = 0; mi < 2; ++mi)
#pragma unroll
        for (int ni = 0; ni < 4; ++ni) {
          acc[2 * q + mi][ni] = __builtin_amdgcn_mfma_f32_16x16x32_f16(
              af[mi][0], bf[ni][0], acc[2 * q + mi][ni], 0, 0, 0);
          acc[2 * q + mi][ni] = __builtin_amdgcn_mfma_f32_16x16x32_f16(
              af[mi][1], bf[ni][1], acc[2 * q + mi][ni], 0, 0, 0);
        }
      __builtin_amdgcn_s_setprio(0);
      asm volatile("s_barrier" ::: "memory");
    }
  }

  // epilogue
  const int fr = l & 15, fq = l >> 4;
  const int r0 = tm * 256 + wr * 128;
  const int c0 = tn * 256 + wc * 64;
#pragma unroll
  for (int m = 0; m < 8; ++m) {
#pragma unroll
    for (int n = 0; n < 4; ++n) {
#pragma unroll
      for (int j = 0; j < 4; ++j) {
        const int r = r0 + m * 16 + fq * 4 + j;
        const int c = c0 + n * 16 + fr;
        float v = acc[m][n][j];
        if constexpr (MODE == 0) {
          outF[((size_t)b * Tt + r) * Ss + c] = v;
        } else if constexpr (MODE == 1) {
          outH[((size_t)b * Tt + r) * Dd + c] = f2h(v);
        } else {
          outF[((size_t)b * Tt + r) * Oo + c] = v + bias[c];
        }
      }
    }
  }
}

// ---------------- column (axis=t) softmax stats: m, 1/l per (b,s) ------------
// block: 512 thr = 8 t-segments x 64 columns; grid (S/64, B). Coalesced.
__global__ __launch_bounds__(512) void colstats(const float* __restrict__ sc,
                                                const u32* __restrict__ bits,
                                                float* __restrict__ mcol,
                                                float* __restrict__ rlcol) {
  const int b = blockIdx.y;
  const int c = threadIdx.x & 63;
  const int seg = threadIdx.x >> 6;  // 0..7, each covers 256 t-rows
  const int s = blockIdx.x * 64 + c;
  const int sh5 = s & 31;
  float m = -3.0e38f, lsum = 0.0f;
#pragma unroll 4
  for (int i = 0; i < 256; ++i) {
    const size_t idx = ((size_t)b * Tt + seg * 256 + i) * Ss + s;
    float v = sc[idx];
    const u32 wbits = bits[idx >> 5];
    v += (float)((wbits >> sh5) & 1u) * NEG_BIG;
    float mn = fmaxf(m, v);
    lsum = lsum * __expf(m - mn) + __expf(v - mn);
    m = mn;
  }
  __shared__ float sm[8][64], sl[8][64];
  sm[seg][c] = m;
  sl[seg][c] = lsum;
  __syncthreads();
  if (seg == 0) {
    float M = sm[0][c];
#pragma unroll
    for (int k = 1; k < 8; ++k) M = fmaxf(M, sm[k][c]);
    float L = 0.0f;
#pragma unroll
    for (int k = 0; k < 8; ++k) L += sl[k][c] * __expf(sm[k][c] - M);
    mcol[(size_t)b * Ss + s] = M;
    rlcol[(size_t)b * Ss + s] = 1.0f / L;
  }
}

// ---------------- normalize: weight f32 (in place, d_out) + fp16 copy --------
__global__ __launch_bounds__(256) void normalize(float* __restrict__ sc,
                                                 const u32* __restrict__ bits,
                                                 const float* __restrict__ mcol,
                                                 const float* __restrict__ rlcol,
                                                 u16* __restrict__ w16) {
  const size_t i = ((size_t)blockIdx.x * 256 + threadIdx.x) * 4;
  const int s = (int)(i & (Ss - 1));
  const int b = (int)(i >> 22);  // T*S = 2^22
  const u32 wbits = bits[i >> 5];
  const int sh5 = s & 31;
  float4 v = *(const float4*)(sc + i);
  float4 m4 = *(const float4*)(mcol + (size_t)b * Ss + s);
  float4 r4 = *(const float4*)(rlcol + (size_t)b * Ss + s);
  float v0 = v.x + (float)((wbits >> (sh5 + 0)) & 1u) * NEG_BIG;
  float v1 = v.y + (float)((wbits >> (sh5 + 1)) & 1u) * NEG_BIG;
  float v2 = v.z + (float)((wbits >> (sh5 + 2)) & 1u) * NEG_BIG;
  float v3 = v.w + (float)((wbits >> (sh5 + 3)) & 1u) * NEG_BIG;
  float w0 = __expf(v0 - m4.x) * r4.x;
  float w1 = __expf(v1 - m4.y) * r4.y;
  float w2 = __expf(v2 - m4.z) * r4.z;
  float w3 = __expf(v3 - m4.w) * r4.w;
  *(float4*)(sc + i) = make_float4(w0, w1, w2, w3);
  *(u16x4*)(w16 + i) = (u16x4){f2h(w0), f2h(w1), f2h(w2), f2h(w3)};
}

extern "C" void kernel_launch(void* const* d_in, const int* in_sizes, int n_in,
                              void* d_out, int out_size, void* d_ws, size_t ws_size,
                              hipStream_t stream) {
  const float* src = (const float*)d_in[0];   // [B,S,D]
  const float* tgt = (const float*)d_in[1];   // [B,T,D]
  const int* mask = (const int*)d_in[2];      // [T,B,S]
  const float* W = (const float*)d_in[3];     // [O,2D]
  const float* bias = (const float*)d_in[4];  // [O]
  float* out = (float*)d_out;                       // [B,T,O]
  float* scores = out + (size_t)Bb * Tt * Oo;       // [B,T,S] (weight output region)

  u16* tgt16 = (u16*)d_ws;                          // fp16 [B,T,D]
  u16* src16 = tgt16 + (size_t)Bb * Tt * Dd;        // fp16 [B,S,D]
  u16* srcT = src16 + (size_t)Bb * Ss * Dd;         // fp16 [B,D,S]
  u16* wsum16 = srcT + (size_t)Bb * Dd * Ss;        // fp16 [B,T,D]
  u16* w16 = wsum16 + (size_t)Bb * Tt * Dd;         // fp16 [B,T,S]
  u16* W16 = w16 + (size_t)Bb * Tt * Ss;            // fp16 [O,2D]
  float* mcol = (float*)(W16 + (size_t)Oo * 2 * Dd);  // [B,S]
  float* rlcol = mcol + (size_t)Bb * Ss;              // [B,S]
  u32* bits = (u32*)wsum16;  // [B,T,S/32] — dead before GEMM2 writes wsum16

  // prep
  pack_mask<<<(Bb * Tt * (Ss / 32)) / 256, 256, 0, stream>>>(mask, bits);
  cvt_f16<<<(Bb * Tt * Dd) / 1024, 256, 0, stream>>>(tgt, tgt16);
  cvt_f16<<<(Oo * 2 * Dd) / 1024, 256, 0, stream>>>(W, W16);
  prep_src<<<dim3(Dd / 64, Ss / 64, Bb), 256, 0, stream>>>(src, src16, srcT);

  // GEMM1: scores = tgt * src^T   (M=T, N=S, K=D; NT=16)
  gemm256<0><<<dim3(Ss / 256, Tt / 256, Bb), 512, 0, stream>>>(
      tgt16, (size_t)Dd, (size_t)Tt * Dd, nullptr,
      src16, (size_t)Dd, (size_t)Ss * Dd, Dd / 64,
      scores, nullptr, nullptr);

  // column softmax over t (mask applied via bitmask)
  colstats<<<dim3(Ss / 64, Bb), 512, 0, stream>>>(scores, bits, mcol, rlcol);
  normalize<<<(size_t)(Bb * Tt) * Ss / 1024, 256, 0, stream>>>(scores, bits, mcol, rlcol, w16);

  // GEMM2: wsum = weight * src  (via srcT; M=T, N=D, K=S; NT=32)
  gemm256<1><<<dim3(Dd / 256, Tt / 256, Bb), 512, 0, stream>>>(
      w16, (size_t)Ss, (size_t)Tt * Ss, nullptr,
      srcT, (size_t)Ss, (size_t)Dd * Ss, Ss / 64,
      nullptr, wsum16, nullptr);

  // GEMM3: out = [wsum|tgt] * W^T + bias  (M=T, N=O, K=2D; NT=32)
  gemm256<2><<<dim3(Oo / 256, Tt / 256, Bb), 512, 0, stream>>>(
      wsum16, (size_t)Dd, (size_t)Tt * Dd, tgt16,
      W16, (size_t)2 * Dd, (size_t)0, 2 * Dd / 64,
      out, nullptr, bias);
}

// Round 6
// 664.253 us; speedup vs baseline: 1.3090x; 1.0058x over previous
//
#include <hip/hip_runtime.h>

#define Bb 8
#define Ss 2048
#define Tt 2048
#define Dd 1024
#define Oo 1024
#define NEG_BIG -1.0e16f

typedef unsigned short u16;
typedef unsigned int u32;
typedef unsigned long long u64;
typedef __attribute__((ext_vector_type(4))) float f32x4;
typedef __attribute__((ext_vector_type(8))) _Float16 f16x8;
typedef __attribute__((ext_vector_type(8))) u16 u16x8;
typedef __attribute__((ext_vector_type(4))) u16 u16x4;

__device__ __forceinline__ u16 f2h(float x) {
  return __builtin_bit_cast(u16, (_Float16)x);
}

__device__ __forceinline__ void gload_lds16(const void* g, void* l) {
  __builtin_amdgcn_global_load_lds(
      (__attribute__((address_space(1))) void*)const_cast<void*>(g),
      (__attribute__((address_space(3))) void*)l, 16, 0, 0);
}

// opaque LDS read: keeps SIInsertWaitcnts from inserting vmcnt(0) hazard waits
// against outstanding global_load_lds (we manage those with counted vmcnt).
// Address passed as a true AS(3) pointer so clang computes the 32-bit LDS
// offset (no aperture-alignment assumption).
__device__ __forceinline__ f16x8 ds_read_b128a(const u16* p) {
  f16x8 r;
  const __attribute__((address_space(3))) u16* lp =
      (const __attribute__((address_space(3))) u16*)p;
  asm volatile("ds_read_b128 %0, %1" : "=v"(r) : "v"(lp));
  return r;
}

union F2U {
  float2 f;
  u64 u;
};

__device__ __forceinline__ void ml_cas(u64* addr, float m, float l) {
  F2U cur;
  cur.u = *((volatile u64*)addr);
  // bounded retry: <=63 contending blocks per word; every failed CAS implies
  // another block committed, so 64 iterations is unreachable in practice.
  for (int it = 0; it < 64; ++it) {
    float M = fmaxf(cur.f.x, m);
    float L = cur.f.y * __expf(cur.f.x - M) + l * __expf(m - M);
    F2U nxt;
    nxt.f.x = M;
    nxt.f.y = L;
    u64 prev = atomicCAS(addr, cur.u, nxt.u);
    if (prev == cur.u) break;
    cur.u = prev;
  }
}

// ---------------- init (m,l) table ----------------
__global__ __launch_bounds__(256) void init_ml(u64* __restrict__ ml) {
  F2U v;
  v.f.x = -3.0e38f;
  v.f.y = 0.0f;
  ml[(size_t)blockIdx.x * 256 + threadIdx.x] = v.u;
}

// ---------------- prep: f32 -> fp16 elementwise ----------------
__global__ __launch_bounds__(256) void cvt_f16(const float* __restrict__ in,
                                               u16* __restrict__ out16) {
  const size_t i = ((size_t)blockIdx.x * 256 + threadIdx.x) * 4;
  float4 v = *(const float4*)(in + i);
  u16x4 h = {f2h(v.x), f2h(v.y), f2h(v.z), f2h(v.w)};
  *(u16x4*)(out16 + i) = h;
}

// ---------------- prep: mask i32 [T,B,S] -> bitmask [B,T,S/32] ---------------
__global__ __launch_bounds__(256) void pack_mask(const int* __restrict__ mask,
                                                 u32* __restrict__ bits) {
  const size_t widx = (size_t)blockIdx.x * 256 + threadIdx.x;
  const int sw = (int)(widx & (Ss / 32 - 1));
  const int t = (int)((widx >> 6) & (Tt - 1));
  const int b = (int)(widx >> 17);
  const int* p = mask + ((size_t)t * Bb + b) * Ss + sw * 32;
  u32 w = 0;
#pragma unroll
  for (int q = 0; q < 8; ++q) {
    int4 v = *(const int4*)(p + q * 4);
    w |= (u32)((v.x != 0) ? 1u : 0u) << (q * 4 + 0);
    w |= (u32)((v.y != 0) ? 1u : 0u) << (q * 4 + 1);
    w |= (u32)((v.z != 0) ? 1u : 0u) << (q * 4 + 2);
    w |= (u32)((v.w != 0) ? 1u : 0u) << (q * 4 + 3);
  }
  bits[widx] = w;
}

// ---------------- prep: src f32 -> src16 fp16 [B,S,D] + srcT fp16 [B,D,S] ----
__global__ __launch_bounds__(256) void prep_src(const float* __restrict__ src,
                                                u16* __restrict__ src16,
                                                u16* __restrict__ srcT) {
  __shared__ u16 tile[64][72];
  const int b = blockIdx.z;
  const int d0 = blockIdx.x * 64;
  const int s0 = blockIdx.y * 64;
  const int tid = threadIdx.x;
  const int sl = tid >> 4;
  const int dl = (tid & 15) * 4;
#pragma unroll
  for (int p = 0; p < 4; ++p) {
    const int srow = s0 + sl + p * 16;
    float4 v = *(const float4*)(src + ((size_t)b * Ss + srow) * Dd + d0 + dl);
    u16 h0 = f2h(v.x), h1 = f2h(v.y), h2 = f2h(v.z), h3 = f2h(v.w);
    *(u16x4*)(src16 + ((size_t)b * Ss + srow) * Dd + d0 + dl) = (u16x4){h0, h1, h2, h3};
    tile[dl + 0][sl + p * 16] = h0;
    tile[dl + 1][sl + p * 16] = h1;
    tile[dl + 2][sl + p * 16] = h2;
    tile[dl + 3][sl + p * 16] = h3;
  }
  __syncthreads();
  const int dl2 = tid >> 4;
  const int sl2 = (tid & 15) * 4;
#pragma unroll
  for (int p = 0; p < 4; ++p) {
    const int drow = d0 + dl2 + p * 16;
    u16x4 vv = {tile[dl2 + p * 16][sl2], tile[dl2 + p * 16][sl2 + 1],
                tile[dl2 + p * 16][sl2 + 2], tile[dl2 + p * 16][sl2 + 3]};
    *(u16x4*)(srcT + ((size_t)b * Dd + drow) * Ss + s0 + sl2) = vv;
  }
}

// ================= 256x256 8-phase GEMM (T2+T3+T4+T5) ========================
// C = A (M x K) * B^T (N x K), fp16 MFMA 16x16x32, BM=BN=256, BK=64.
// MODE 0: scores = tgt16*src16^T, +mask (bits) in epilogue, online (m,l) CAS -> f32
// MODE 1: wsum   = w16 * srcT^T  -> fp16
// MODE 2: out    = [wsum|tgt16] * W16^T + bias -> f32
template <int MODE>
__global__ __launch_bounds__(512) void gemm256(
    const u16* __restrict__ A, size_t ldA, size_t sA,
    const u16* __restrict__ A2,
    const u16* __restrict__ Bm, size_t ldB, size_t sB,
    int NT,
    float* __restrict__ outF, u16* __restrict__ outH,
    const float* __restrict__ bias,
    const u32* __restrict__ bits, u64* __restrict__ ml) {
  __shared__ __align__(16) u16 sh[66560];
  const int b = blockIdx.z;
  const int tn = blockIdx.x, tm = blockIdx.y;
  const int tid = threadIdx.x;
  const int w = tid >> 6, l = tid & 63;
  const int wr = w >> 2, wc = w & 3;

  const int sr0 = w * 16 + (l >> 3);
  const int scb = (((l & 7) ^ (l >> 3)) << 4);
  const int fc0 = (((l >> 4) * 16) ^ ((l & 7) << 4)) >> 1;
  const int fc1 = ((64 + (l >> 4) * 16) ^ ((l & 7) << 4)) >> 1;

  auto STAGE = [&](int isB, int ds, int hh, int ts) {
    int dst = (isB ? 32768 : 0) + ds * 16384 + hh * 8192 + w * 1024;
    if (ts >= NT) { ts = NT - 1; dst = 65536; }
    const u16* srcBase;
    size_t ld;
    int rowBase;
    int kbyte = ts * 128;
    if (isB) {
      srcBase = Bm + (size_t)b * sB;
      ld = ldB;
      rowBase = tn * 256 + hh * 128;
    } else {
      if constexpr (MODE == 2) {
        srcBase = (ts < 16 ? A : A2) + (size_t)b * sA;
        kbyte = (ts & 15) * 128;
      } else {
        srcBase = A + (size_t)b * sA;
      }
      ld = ldA;
      rowBase = tm * 256 + hh * 128;
    }
    const char* s0 = (const char*)srcBase + (size_t)(rowBase + sr0) * (ld * 2) + kbyte + scb;
    const char* s1 = (const char*)srcBase + (size_t)(rowBase + sr0 + 8) * (ld * 2) + kbyte + scb;
    gload_lds16(s0, &sh[dst]);
    gload_lds16(s1, &sh[dst + 512]);
  };

  f32x4 acc[8][4];
#pragma unroll
  for (int m = 0; m < 8; ++m)
#pragma unroll
    for (int n = 0; n < 4; ++n) acc[m][n] = (f32x4){0.f, 0.f, 0.f, 0.f};
  f16x8 bf[4][2], af[2][2];

  // prologue: H0..H5 = B(0)h0, B(0)h1, A(0)h0, A(0)h1, B(1)h0, B(1)h1
  STAGE(1, 0, 0, 0);
  STAGE(1, 0, 1, 0);
  STAGE(0, 0, 0, 0);
  STAGE(0, 0, 1, 0);
  STAGE(1, 1, 0, 1);
  STAGE(1, 1, 1, 1);
  asm volatile("s_waitcnt vmcnt(4)" ::: "memory");
  asm volatile("s_barrier" ::: "memory");

  const int NITER = NT >> 1;
  for (int it = 0; it < NITER; ++it) {
#pragma unroll
    for (int p = 0; p < 8; ++p) {
      const int q = p & 3, d = (p >> 2) & 1;
      if (q == 0) {
#pragma unroll
        for (int ni = 0; ni < 4; ++ni) {
          const int rb = wc * 64 + ni * 16 + (l & 15);
          bf[ni][0] = ds_read_b128a(&sh[32768 + d * 16384 + rb * 64 + fc0]);
          bf[ni][1] = ds_read_b128a(&sh[32768 + d * 16384 + rb * 64 + fc1]);
        }
      }
#pragma unroll
      for (int mi = 0; mi < 2; ++mi) {
        const int ra = wr * 128 + q * 32 + mi * 16 + (l & 15);
        af[mi][0] = ds_read_b128a(&sh[d * 16384 + ra * 64 + fc0]);
        af[mi][1] = ds_read_b128a(&sh[d * 16384 + ra * 64 + fc1]);
      }
      {
        const int j = 8 * it + p + 6;
        const int ts = j >> 2, sub = j & 3;
        STAGE(sub < 2, ts & 1, sub & 1, ts);
      }
      if (q == 3) asm volatile("s_waitcnt vmcnt(4)" ::: "memory");
      asm volatile("s_barrier" ::: "memory");
      asm volatile("s_waitcnt lgkmcnt(0)" ::: "memory");
      __builtin_amdgcn_sched_barrier(0);
      __builtin_amdgcn_s_setprio(1);
#pragma unroll
      for (int mi = 0; mi < 2; ++mi)
#pragma unroll
        for (int ni = 0; ni < 4; ++ni) {
          acc[2 * q + mi][ni] = __builtin_amdgcn_mfma_f32_16x16x32_f16(
              af[mi][0], bf[ni][0], acc[2 * q + mi][ni], 0, 0, 0);
          acc[2 * q + mi][ni] = __builtin_amdgcn_mfma_f32_16x16x32_f16(
              af[mi][1], bf[ni][1], acc[2 * q + mi][ni], 0, 0, 0);
        }
      __builtin_amdgcn_sched_barrier(0);
      __builtin_amdgcn_s_setprio(0);
      asm volatile("s_barrier" ::: "memory");
    }
  }

  // epilogue
  const int fr = l & 15, fq = l >> 4;
  const int r0 = tm * 256 + wr * 128;
  const int c0 = tn * 256 + wc * 64;
  if constexpr (MODE == 0) {
    float cm[4], cl[4];
#pragma unroll
    for (int n = 0; n < 4; ++n) { cm[n] = -3.0e38f; cl[n] = 0.0f; }
#pragma unroll
    for (int m = 0; m < 8; ++m) {
#pragma unroll
      for (int j = 0; j < 4; ++j) {
        const int gr = r0 + m * 16 + fq * 4 + j;
        const u32* bw = bits + ((size_t)b * Tt + gr) * (Ss / 32) + (c0 >> 5);
        const u32 w0 = bw[0], w1 = bw[1];
        float* orow = outF + ((size_t)b * Tt + gr) * Ss + c0 + fr;
#pragma unroll
        for (int n = 0; n < 4; ++n) {
          const u32 ww = (n & 2) ? w1 : w0;
          float v = acc[m][n][j] + (float)((ww >> ((n & 1) * 16 + fr)) & 1u) * NEG_BIG;
          orow[n * 16] = v;
          float M = fmaxf(cm[n], v);
          cl[n] = cl[n] * __expf(cm[n] - M) + __expf(v - M);
          cm[n] = M;
        }
      }
    }
#pragma unroll
    for (int n = 0; n < 4; ++n) {
#pragma unroll
      for (int off = 16; off < 64; off <<= 1) {
        float om = __shfl_xor(cm[n], off);
        float ol = __shfl_xor(cl[n], off);
        float M = fmaxf(cm[n], om);
        cl[n] = cl[n] * __expf(cm[n] - M) + ol * __expf(om - M);
        cm[n] = M;
      }
    }
    if (l < 16) {
#pragma unroll
      for (int n = 0; n < 4; ++n)
        ml_cas(ml + (size_t)b * Ss + c0 + n * 16 + l, cm[n], cl[n]);
    }
  } else {
#pragma unroll
    for (int m = 0; m < 8; ++m) {
#pragma unroll
      for (int n = 0; n < 4; ++n) {
#pragma unroll
        for (int j = 0; j < 4; ++j) {
          const int r = r0 + m * 16 + fq * 4 + j;
          const int c = c0 + n * 16 + fr;
          float v = acc[m][n][j];
          if constexpr (MODE == 1) {
            outH[((size_t)b * Tt + r) * Dd + c] = f2h(v);
          } else {
            outF[((size_t)b * Tt + r) * Oo + c] = v + bias[c];
          }
        }
      }
    }
  }
}

// ---------------- normalize: weight f32 (in place, d_out) + fp16 copy --------
__global__ __launch_bounds__(256) void normalize(float* __restrict__ sc,
                                                 const u64* __restrict__ ml,
                                                 u16* __restrict__ w16) {
  const size_t i = ((size_t)blockIdx.x * 256 + threadIdx.x) * 4;
  const int s = (int)(i & (Ss - 1));
  const int b = (int)(i >> 22);  // T*S = 2^22
  float4 v = *(const float4*)(sc + i);
  const float* mlp = (const float*)(ml + (size_t)b * Ss + s);
  float4 a = *(const float4*)(mlp);      // m0,l0,m1,l1
  float4 c = *(const float4*)(mlp + 4);  // m2,l2,m3,l3
  float w0 = __expf(v.x - a.x) / a.y;
  float w1 = __expf(v.y - a.z) / a.w;
  float w2 = __expf(v.z - c.x) / c.y;
  float w3 = __expf(v.w - c.z) / c.w;
  *(float4*)(sc + i) = make_float4(w0, w1, w2, w3);
  *(u16x4*)(w16 + i) = (u16x4){f2h(w0), f2h(w1), f2h(w2), f2h(w3)};
}

extern "C" void kernel_launch(void* const* d_in, const int* in_sizes, int n_in,
                              void* d_out, int out_size, void* d_ws, size_t ws_size,
                              hipStream_t stream) {
  const float* src = (const float*)d_in[0];   // [B,S,D]
  const float* tgt = (const float*)d_in[1];   // [B,T,D]
  const int* mask = (const int*)d_in[2];      // [T,B,S]
  const float* W = (const float*)d_in[3];     // [O,2D]
  const float* bias = (const float*)d_in[4];  // [O]
  float* out = (float*)d_out;                       // [B,T,O]
  float* scores = out + (size_t)Bb * Tt * Oo;       // [B,T,S] (weight output region)

  u16* tgt16 = (u16*)d_ws;                          // fp16 [B,T,D]
  u16* src16 = tgt16 + (size_t)Bb * Tt * Dd;        // fp16 [B,S,D]
  u16* srcT = src16 + (size_t)Bb * Ss * Dd;         // fp16 [B,D,S]
  u16* wsum16 = srcT + (size_t)Bb * Dd * Ss;        // fp16 [B,T,D]
  u16* w16 = wsum16 + (size_t)Bb * Tt * Dd;         // fp16 [B,T,S]
  u16* W16 = w16 + (size_t)Bb * Tt * Ss;            // fp16 [O,2D]
  u64* ml = (u64*)(W16 + (size_t)Oo * 2 * Dd);      // (m,l) [B,S]
  u32* bits = (u32*)wsum16;  // [B,T,S/32] — dead before GEMM2 writes wsum16

  // prep
  init_ml<<<(Bb * Ss) / 256, 256, 0, stream>>>(ml);
  pack_mask<<<(Bb * Tt * (Ss / 32)) / 256, 256, 0, stream>>>(mask, bits);
  cvt_f16<<<(Bb * Tt * Dd) / 1024, 256, 0, stream>>>(tgt, tgt16);
  cvt_f16<<<(Oo * 2 * Dd) / 1024, 256, 0, stream>>>(W, W16);
  prep_src<<<dim3(Dd / 64, Ss / 64, Bb), 256, 0, stream>>>(src, src16, srcT);

  // GEMM1: scores = tgt * src^T + mask, fused column (m,l) stats
  gemm256<0><<<dim3(Ss / 256, Tt / 256, Bb), 512, 0, stream>>>(
      tgt16, (size_t)Dd, (size_t)Tt * Dd, nullptr,
      src16, (size_t)Dd, (size_t)Ss * Dd, Dd / 64,
      scores, nullptr, nullptr, bits, ml);

  // normalize: weight = exp(score - m)/l  (f32 in d_out, fp16 copy for GEMM2)
  normalize<<<(size_t)(Bb * Tt) * Ss / 1024, 256, 0, stream>>>(scores, ml, w16);

  // GEMM2: wsum = weight * src  (via srcT; M=T, N=D, K=S; NT=32)
  gemm256<1><<<dim3(Dd / 256, Tt / 256, Bb), 512, 0, stream>>>(
      w16, (size_t)Ss, (size_t)Tt * Ss, nullptr,
      srcT, (size_t)Ss, (size_t)Dd * Ss, Ss / 64,
      nullptr, wsum16, nullptr, nullptr, nullptr);

  // GEMM3: out = [wsum|tgt] * W^T + bias  (M=T, N=O, K=2D; NT=32)
  gemm256<2><<<dim3(Oo / 256, Tt / 256, Bb), 512, 0, stream>>>(
      wsum16, (size_t)Dd, (size_t)Tt * Dd, tgt16,
      W16, (size_t)2 * Dd, (size_t)0, 2 * Dd / 64,
      out, nullptr, bias, nullptr, nullptr);
}